// Round 1
// 293.331 us; speedup vs baseline: 1.3957x; 1.3957x over previous
//
#include <hip/hip_runtime.h>
#include <hip/hip_fp16.h>

#define IN_DIM 256
#define OUT_DIM 128
#define SLOPE 0.1f

typedef __attribute__((ext_vector_type(8))) short short8;
typedef __attribute__((ext_vector_type(4))) float f32x4;

// round-to-nearest-even f32 -> bf16 bits
__device__ __forceinline__ unsigned bf16_rne(float f) {
    unsigned u = __float_as_uint(f);
    return (u + 0x7FFFu + ((u >> 16) & 1u)) >> 16;
}

// ---------------------------------------------------------------------------
// K0: pre-split W into bf16 hi/lo once (was re-converted by every GEMM block)
// ---------------------------------------------------------------------------
__global__ __launch_bounds__(256) void wsplit_kernel(
    const float* __restrict__ W, short* __restrict__ Whi, short* __restrict__ Wlo)
{
    const int i = blockIdx.x * 256 + threadIdx.x;   // 128*256 = 32768 elements
    const float v = W[i];
    const unsigned hb = bf16_rne(v);
    const float hf = __uint_as_float(hb << 16);
    Whi[i] = (short)hb;
    Wlo[i] = (short)bf16_rne(v - hf);
}

// ---------------------------------------------------------------------------
// K1: emb = x @ W^T + b  via split-bf16 MFMA (3 terms).
// Fused epilogue: s1 = emb.a1, s2 = emb.a2 (from fp32 acc), emb stored fp16.
// Tile 128m x 128n x 32k, 4 waves (each 32m x 128n), kc-major chunk LDS.
// ---------------------------------------------------------------------------
__global__ __launch_bounds__(256) void gemm_emb_kernel(
    const float* __restrict__ x, const short* __restrict__ Whi_g,
    const short* __restrict__ Wlo_g, const float* __restrict__ bias,
    const float* __restrict__ a, __half* __restrict__ emb_h,
    float* __restrict__ s1, float* __restrict__ s2, int N)
{
    // staging uses [0,16384) shorts; epilogue repack uses [0,18432) as half[128][144]
    __shared__ short lds[128 * 144];
    short* Ahi = lds;
    short* Alo = lds + 4096;
    short* Bhi = lds + 8192;
    short* Blo = lds + 12288;

    const int tid = threadIdx.x;
    const int l   = tid & 63;
    const int w   = tid >> 6;
    const int gm0 = blockIdx.x * 128;

    const int sm  = tid >> 1;          // staging row 0..127
    const int kc0 = (tid & 1) * 2;     // staging chunk pair {0,1} or {2,3}

    f32x4 acc[2][8];
    #pragma unroll
    for (int i = 0; i < 2; ++i)
        #pragma unroll
        for (int j = 0; j < 8; ++j) acc[i][j] = (f32x4)0.f;

    float bias_v[8], av1[8], av2[8];
    #pragma unroll
    for (int nf = 0; nf < 8; ++nf) {
        const int col = nf * 16 + (l & 15);
        bias_v[nf] = bias[col];
        av1[nf]    = a[col];
        av2[nf]    = a[OUT_DIM + col];
    }

    for (int ks = 0; ks < 8; ++ks) {
        const int k0 = ks * 32;
        #pragma unroll
        for (int q = 0; q < 2; ++q) {
            const int kc = kc0 + q;
            // A from x: guarded, f32 -> bf16 hi/lo split
            {
                const int gm = gm0 + sm;
                float v[8];
                if (gm < N) {
                    const float4 p0 = *(const float4*)&x[(size_t)gm * IN_DIM + k0 + kc * 8];
                    const float4 p1 = *(const float4*)&x[(size_t)gm * IN_DIM + k0 + kc * 8 + 4];
                    v[0]=p0.x; v[1]=p0.y; v[2]=p0.z; v[3]=p0.w;
                    v[4]=p1.x; v[5]=p1.y; v[6]=p1.z; v[7]=p1.w;
                } else {
                    #pragma unroll
                    for (int j = 0; j < 8; ++j) v[j] = 0.f;
                }
                short8 h8, l8;
                #pragma unroll
                for (int j = 0; j < 8; ++j) {
                    unsigned hb = bf16_rne(v[j]);
                    float hf = __uint_as_float(hb << 16);
                    h8[j] = (short)hb;
                    l8[j] = (short)bf16_rne(v[j] - hf);
                }
                *(short8*)&Ahi[kc * 1024 + sm * 8] = h8;
                *(short8*)&Alo[kc * 1024 + sm * 8] = l8;
            }
            // B from pre-split W: pure copy, no conversion math
            {
                const short8 h8 = *(const short8*)&Whi_g[sm * IN_DIM + k0 + kc * 8];
                const short8 l8 = *(const short8*)&Wlo_g[sm * IN_DIM + k0 + kc * 8];
                *(short8*)&Bhi[kc * 1024 + sm * 8] = h8;
                *(short8*)&Blo[kc * 1024 + sm * 8] = l8;
            }
        }
        __syncthreads();

        short8 ah[2], al[2];
        #pragma unroll
        for (int mf = 0; mf < 2; ++mf) {
            const int row = w * 32 + mf * 16 + (l & 15);
            const int off = (l >> 4) * 1024 + row * 8;
            ah[mf] = *(const short8*)&Ahi[off];
            al[mf] = *(const short8*)&Alo[off];
        }
        #pragma unroll
        for (int nf = 0; nf < 8; ++nf) {
            const int col = nf * 16 + (l & 15);
            const int off = (l >> 4) * 1024 + col * 8;
            short8 bh = *(const short8*)&Bhi[off];
            short8 bl = *(const short8*)&Blo[off];
            #pragma unroll
            for (int mf = 0; mf < 2; ++mf) {
                acc[mf][nf] = __builtin_amdgcn_mfma_f32_16x16x32_bf16(ah[mf], bh, acc[mf][nf], 0, 0, 0);
                acc[mf][nf] = __builtin_amdgcn_mfma_f32_16x16x32_bf16(al[mf], bh, acc[mf][nf], 0, 0, 0);
                acc[mf][nf] = __builtin_amdgcn_mfma_f32_16x16x32_bf16(ah[mf], bl, acc[mf][nf], 0, 0, 0);
            }
        }
        __syncthreads();
    }

    // ---- fused epilogue: bias, s1/s2 (fp32), emb -> fp16 via LDS repack ----
    __half* hl = (__half*)lds;   // [128][144] halves, padded for bank spread
    #pragma unroll
    for (int mf = 0; mf < 2; ++mf) {
        #pragma unroll
        for (int r = 0; r < 4; ++r) {
            const int lrow = w * 32 + mf * 16 + (l >> 4) * 4 + r;
            float p1 = 0.f, p2 = 0.f;
            #pragma unroll
            for (int nf = 0; nf < 8; ++nf) {
                const float e = acc[mf][nf][r] + bias_v[nf];
                p1 += e * av1[nf];
                p2 += e * av2[nf];
                hl[lrow * 144 + nf * 16 + (l & 15)] = __float2half(e);
            }
            p1 += __shfl_xor(p1, 1); p1 += __shfl_xor(p1, 2);
            p1 += __shfl_xor(p1, 4); p1 += __shfl_xor(p1, 8);
            p2 += __shfl_xor(p2, 1); p2 += __shfl_xor(p2, 2);
            p2 += __shfl_xor(p2, 4); p2 += __shfl_xor(p2, 8);
            const int gm = gm0 + lrow;
            if ((l & 15) == 0 && gm < N) { s1[gm] = p1; s2[gm] = p2; }
        }
    }
    __syncthreads();
    // coalesced copy LDS fp16 -> global emb_h (row = 128 halves = 16 uint4)
    #pragma unroll
    for (int i = 0; i < 8; ++i) {
        const int idx = i * 256 + tid;      // 2048 uint4 total
        const int row = idx >> 4, seg = idx & 15;
        if (gm0 + row < N) {
            const uint4 u = *(const uint4*)&hl[row * 144 + seg * 8];
            ((uint4*)emb_h)[(size_t)(gm0 + row) * 16 + seg] = u;
        }
    }
}

// ---------------------------------------------------------------------------
// CSR build: degree -> scan -> fill.  deg[] reused as fill cursor.
// ---------------------------------------------------------------------------
__global__ __launch_bounds__(256) void degree_kernel(
    const int* __restrict__ edges, int* __restrict__ deg, int E)
{
    const int e = blockIdx.x * 256 + threadIdx.x;
    if (e >= E) return;
    const int2 ed = ((const int2*)edges)[e];
    atomicAdd(&deg[ed.x], 1);
}

__global__ __launch_bounds__(256) void scan1_kernel(
    const int* __restrict__ deg, int* __restrict__ off,
    int* __restrict__ bsum, int N)
{
    __shared__ int lds[256];
    const int t = threadIdx.x;
    const int base = blockIdx.x * 1024 + t * 4;
    int v[4];
    int ts = 0;
    #pragma unroll
    for (int j = 0; j < 4; ++j) {
        v[j] = (base + j < N) ? deg[base + j] : 0;
        ts += v[j];
    }
    lds[t] = ts;
    __syncthreads();
    for (int d = 1; d < 256; d <<= 1) {
        int xv = (t >= d) ? lds[t - d] : 0;
        __syncthreads();
        lds[t] += xv;
        __syncthreads();
    }
    int run = lds[t] - ts;
    #pragma unroll
    for (int j = 0; j < 4; ++j) {
        if (base + j < N) off[base + j] = run;
        run += v[j];
    }
    if (t == 255) bsum[blockIdx.x] = lds[255];
}

__global__ __launch_bounds__(256) void scan2_kernel(int* __restrict__ bsum, int nb)
{
    __shared__ int lds[256];
    const int t = threadIdx.x;
    const int v = (t < nb) ? bsum[t] : 0;
    lds[t] = v;
    __syncthreads();
    for (int d = 1; d < 256; d <<= 1) {
        int xv = (t >= d) ? lds[t - d] : 0;
        __syncthreads();
        lds[t] += xv;
        __syncthreads();
    }
    if (t < nb) bsum[t] = lds[t] - v;
}

__global__ __launch_bounds__(256) void scan3_kernel(
    int* __restrict__ off, const int* __restrict__ bsum,
    int* __restrict__ deg, int N, int E)
{
    const int i = blockIdx.x * 256 + threadIdx.x;
    if (i < N) {
        off[i] += bsum[i >> 10];
        deg[i] = 0;
    }
    if (i == 0) off[N] = E;
}

// fill now also computes the edge score once (was computed 16x redundantly
// per lane in agg) and packs (dst, score) into one float2 for a single load.
__global__ __launch_bounds__(256) void fill_kernel(
    const int* __restrict__ edges, const int* __restrict__ off,
    int* __restrict__ cursor, const float* __restrict__ s1,
    const float* __restrict__ s2, float2* __restrict__ edata, int E)
{
    const int e = blockIdx.x * 256 + threadIdx.x;
    if (e >= E) return;
    const int2 ed = ((const int2*)edges)[e];
    const int pos = atomicAdd(&cursor[ed.x], 1);
    const float ll = s1[ed.x] + s2[ed.y];
    const float sc = __expf(ll > 0.f ? ll : SLOPE * ll);
    edata[off[ed.x] + pos] = make_float2(__int_as_float(ed.y), sc);
}

// ---------------------------------------------------------------------------
// K3: gather aggregation. Wave = 4 edge-groups x 16 col-lanes.
// Each 16-lane group owns one edge: reads (dst,score) pair, gathers its 16B
// slice of the 256B fp16 row. No per-edge shfl chain; 8 edges in flight/iter.
// ---------------------------------------------------------------------------
__global__ __launch_bounds__(256) void agg_kernel(
    const int* __restrict__ off, const float2* __restrict__ edata,
    const __half* __restrict__ emb_h, float* __restrict__ results, int N)
{
    const int wid  = (int)((blockIdx.x * 256u + threadIdx.x) >> 6);
    const int lane = threadIdx.x & 63;
    if (wid >= N) return;
    const int eg = lane >> 4;     // edge sub-group 0..3
    const int cl = lane & 15;     // column segment (8 halves = 16B)
    const int beg = off[wid];
    const int end = off[wid + 1];

    const float4* __restrict__ embrow = (const float4*)emb_h;  // 16 float4/row

    float av[8];
    #pragma unroll
    for (int k = 0; k < 8; ++k) av[k] = 0.f;
    float rs = 0.f;

    for (int base = beg; base < end; base += 8) {
        #pragma unroll
        for (int q = 0; q < 2; ++q) {
            const int idx = base + q * 4 + eg;
            int d = 0;
            float sc = 0.f;
            if (idx < end) {
                const float2 ed = edata[idx];
                d  = __float_as_int(ed.x);
                sc = ed.y;
            }
            rs += sc;
            const float4 v = embrow[(size_t)d * 16 + cl];
            const __half2* hp = reinterpret_cast<const __half2*>(&v);
            #pragma unroll
            for (int k = 0; k < 4; ++k) {
                const float2 f = __half22float2(hp[k]);
                av[2 * k]     += sc * f.x;
                av[2 * k + 1] += sc * f.y;
            }
        }
    }

    // reduce across the 4 edge-groups (lanes differing in bits 4,5)
    #pragma unroll
    for (int k = 0; k < 8; ++k) {
        av[k] += __shfl_xor(av[k], 16);
        av[k] += __shfl_xor(av[k], 32);
    }
    rs += __shfl_xor(rs, 16);
    rs += __shfl_xor(rs, 32);

    const float inv = 1.f / (rs > 0.f ? rs : 1.f);
    if (eg == 0) {
        float4* rp = (float4*)&results[(size_t)wid * 128 + cl * 8];
        rp[0] = make_float4(av[0] * inv, av[1] * inv, av[2] * inv, av[3] * inv);
        rp[1] = make_float4(av[4] * inv, av[5] * inv, av[6] * inv, av[7] * inv);
    }
}

// ---------------------------------------------------------------------------
// K4: out[i] = results[batch_idx[i]]
// ---------------------------------------------------------------------------
__global__ __launch_bounds__(256) void gather_kernel(
    const float* __restrict__ results, const int* __restrict__ bidx,
    float* __restrict__ out, int N)
{
    const unsigned i = blockIdx.x * 256u + threadIdx.x;
    if (i >= (unsigned)N * 32u) return;
    const unsigned n = i >> 5, c = i & 31;
    ((float4*)out)[i] = ((const float4*)results)[(size_t)bidx[n] * 32 + c];
}

extern "C" void kernel_launch(void* const* d_in, const int* in_sizes, int n_in,
                              void* d_out, int out_size, void* d_ws, size_t ws_size,
                              hipStream_t stream) {
    const float* x     = (const float*)d_in[0];
    const float* W     = (const float*)d_in[1];
    const float* b     = (const float*)d_in[2];
    const float* a     = (const float*)d_in[3];
    const int*   edges = (const int*)d_in[4];
    const int*   bidx  = (const int*)d_in[5];

    const int N = in_sizes[5];
    const int E = in_sizes[4] / 2;

    // workspace layout (edata first for 8B alignment)
    float2* edata   = (float2*)d_ws;
    float*  results = (float*)(edata + E);
    __half* emb_h   = (__half*)(results + (size_t)N * OUT_DIM);
    float*  s1      = (float*)(emb_h + (size_t)N * OUT_DIM);
    float*  s2      = s1 + N;
    int*    deg     = (int*)(s2 + N);
    int*    off     = deg + N;
    int*    bsum    = off + N + 1;
    short*  Whi     = (short*)(bsum + 256);
    short*  Wlo     = Whi + OUT_DIM * IN_DIM;

    hipMemsetAsync(deg, 0, (size_t)N * sizeof(int), stream);

    wsplit_kernel<<<(OUT_DIM * IN_DIM) / 256, 256, 0, stream>>>(W, Whi, Wlo);

    dim3 gGemm((N + 127) / 128);
    gemm_emb_kernel<<<gGemm, 256, 0, stream>>>(x, Whi, Wlo, b, a, emb_h, s1, s2, N);

    const int gE = (E + 255) / 256;
    degree_kernel<<<gE, 256, 0, stream>>>(edges, deg, E);

    const int nb = (N + 1023) / 1024;
    scan1_kernel<<<nb, 256, 0, stream>>>(deg, off, bsum, N);
    scan2_kernel<<<1, 256, 0, stream>>>(bsum, nb);
    scan3_kernel<<<(N + 255) / 256, 256, 0, stream>>>(off, bsum, deg, N, E);

    fill_kernel<<<gE, 256, 0, stream>>>(edges, off, deg, s1, s2, edata, E);

    const unsigned aggThreads = (unsigned)N * 64u;
    agg_kernel<<<(aggThreads + 255u) / 256u, 256, 0, stream>>>(
        off, edata, emb_h, results, N);

    const unsigned gatherThreads = (unsigned)N * 32u;
    gather_kernel<<<(gatherThreads + 255u) / 256u, 256, 0, stream>>>(
        results, bidx, (float*)d_out, N);
}

// Round 2
// 241.118 us; speedup vs baseline: 1.6979x; 1.2165x over previous
//
#include <hip/hip_runtime.h>
#include <hip/hip_fp16.h>

#define IN_DIM 256
#define OUT_DIM 128
#define SLOPE 0.1f

typedef __attribute__((ext_vector_type(8))) short short8;
typedef __attribute__((ext_vector_type(4))) float f32x4;

// round-to-nearest-even f32 -> bf16 bits
__device__ __forceinline__ unsigned bf16_rne(float f) {
    unsigned u = __float_as_uint(f);
    return (u + 0x7FFFu + ((u >> 16) & 1u)) >> 16;
}

// ---------------------------------------------------------------------------
// K0: pre-split W into bf16 hi/lo once
// ---------------------------------------------------------------------------
__global__ __launch_bounds__(256) void wsplit_kernel(
    const float* __restrict__ W, short* __restrict__ Whi, short* __restrict__ Wlo)
{
    const int i = blockIdx.x * 256 + threadIdx.x;   // 128*256 = 32768 elements
    const float v = W[i];
    const unsigned hb = bf16_rne(v);
    const float hf = __uint_as_float(hb << 16);
    Whi[i] = (short)hb;
    Wlo[i] = (short)bf16_rne(v - hf);
}

// ---------------------------------------------------------------------------
// K1: emb = x @ W^T + b via split-bf16 MFMA (3 terms).
// Fused epilogue: s1 = emb.a1, s2 = emb.a2 (fp32 acc), emb stored fp16.
// ---------------------------------------------------------------------------
__global__ __launch_bounds__(256) void gemm_emb_kernel(
    const float* __restrict__ x, const short* __restrict__ Whi_g,
    const short* __restrict__ Wlo_g, const float* __restrict__ bias,
    const float* __restrict__ a, __half* __restrict__ emb_h,
    float* __restrict__ s1, float* __restrict__ s2, int N)
{
    __shared__ short lds[128 * 144];
    short* Ahi = lds;
    short* Alo = lds + 4096;
    short* Bhi = lds + 8192;
    short* Blo = lds + 12288;

    const int tid = threadIdx.x;
    const int l   = tid & 63;
    const int w   = tid >> 6;
    const int gm0 = blockIdx.x * 128;

    const int sm  = tid >> 1;
    const int kc0 = (tid & 1) * 2;

    f32x4 acc[2][8];
    #pragma unroll
    for (int i = 0; i < 2; ++i)
        #pragma unroll
        for (int j = 0; j < 8; ++j) acc[i][j] = (f32x4)0.f;

    float bias_v[8], av1[8], av2[8];
    #pragma unroll
    for (int nf = 0; nf < 8; ++nf) {
        const int col = nf * 16 + (l & 15);
        bias_v[nf] = bias[col];
        av1[nf]    = a[col];
        av2[nf]    = a[OUT_DIM + col];
    }

    for (int ks = 0; ks < 8; ++ks) {
        const int k0 = ks * 32;
        #pragma unroll
        for (int q = 0; q < 2; ++q) {
            const int kc = kc0 + q;
            {
                const int gm = gm0 + sm;
                float v[8];
                if (gm < N) {
                    const float4 p0 = *(const float4*)&x[(size_t)gm * IN_DIM + k0 + kc * 8];
                    const float4 p1 = *(const float4*)&x[(size_t)gm * IN_DIM + k0 + kc * 8 + 4];
                    v[0]=p0.x; v[1]=p0.y; v[2]=p0.z; v[3]=p0.w;
                    v[4]=p1.x; v[5]=p1.y; v[6]=p1.z; v[7]=p1.w;
                } else {
                    #pragma unroll
                    for (int j = 0; j < 8; ++j) v[j] = 0.f;
                }
                short8 h8, l8;
                #pragma unroll
                for (int j = 0; j < 8; ++j) {
                    unsigned hb = bf16_rne(v[j]);
                    float hf = __uint_as_float(hb << 16);
                    h8[j] = (short)hb;
                    l8[j] = (short)bf16_rne(v[j] - hf);
                }
                *(short8*)&Ahi[kc * 1024 + sm * 8] = h8;
                *(short8*)&Alo[kc * 1024 + sm * 8] = l8;
            }
            {
                const short8 h8 = *(const short8*)&Whi_g[sm * IN_DIM + k0 + kc * 8];
                const short8 l8 = *(const short8*)&Wlo_g[sm * IN_DIM + k0 + kc * 8];
                *(short8*)&Bhi[kc * 1024 + sm * 8] = h8;
                *(short8*)&Blo[kc * 1024 + sm * 8] = l8;
            }
        }
        __syncthreads();

        short8 ah[2], al[2];
        #pragma unroll
        for (int mf = 0; mf < 2; ++mf) {
            const int row = w * 32 + mf * 16 + (l & 15);
            const int off = (l >> 4) * 1024 + row * 8;
            ah[mf] = *(const short8*)&Ahi[off];
            al[mf] = *(const short8*)&Alo[off];
        }
        #pragma unroll
        for (int nf = 0; nf < 8; ++nf) {
            const int col = nf * 16 + (l & 15);
            const int off = (l >> 4) * 1024 + col * 8;
            short8 bh = *(const short8*)&Bhi[off];
            short8 bl = *(const short8*)&Blo[off];
            #pragma unroll
            for (int mf = 0; mf < 2; ++mf) {
                acc[mf][nf] = __builtin_amdgcn_mfma_f32_16x16x32_bf16(ah[mf], bh, acc[mf][nf], 0, 0, 0);
                acc[mf][nf] = __builtin_amdgcn_mfma_f32_16x16x32_bf16(al[mf], bh, acc[mf][nf], 0, 0, 0);
                acc[mf][nf] = __builtin_amdgcn_mfma_f32_16x16x32_bf16(ah[mf], bl, acc[mf][nf], 0, 0, 0);
            }
        }
        __syncthreads();
    }

    // ---- fused epilogue ----
    __half* hl = (__half*)lds;   // [128][144]
    #pragma unroll
    for (int mf = 0; mf < 2; ++mf) {
        #pragma unroll
        for (int r = 0; r < 4; ++r) {
            const int lrow = w * 32 + mf * 16 + (l >> 4) * 4 + r;
            float p1 = 0.f, p2 = 0.f;
            #pragma unroll
            for (int nf = 0; nf < 8; ++nf) {
                const float e = acc[mf][nf][r] + bias_v[nf];
                p1 += e * av1[nf];
                p2 += e * av2[nf];
                hl[lrow * 144 + nf * 16 + (l & 15)] = __float2half(e);
            }
            p1 += __shfl_xor(p1, 1); p1 += __shfl_xor(p1, 2);
            p1 += __shfl_xor(p1, 4); p1 += __shfl_xor(p1, 8);
            p2 += __shfl_xor(p2, 1); p2 += __shfl_xor(p2, 2);
            p2 += __shfl_xor(p2, 4); p2 += __shfl_xor(p2, 8);
            const int gm = gm0 + lrow;
            if ((l & 15) == 0 && gm < N) { s1[gm] = p1; s2[gm] = p2; }
        }
    }
    __syncthreads();
    #pragma unroll
    for (int i = 0; i < 8; ++i) {
        const int idx = i * 256 + tid;
        const int row = idx >> 4, seg = idx & 15;
        if (gm0 + row < N) {
            const uint4 u = *(const uint4*)&hl[row * 144 + seg * 8];
            ((uint4*)emb_h)[(size_t)(gm0 + row) * 16 + seg] = u;
        }
    }
}

// ---------------------------------------------------------------------------
// rank: deg counting + per-edge rank in ONE atomic pass (rank write coalesced).
// 2 edges/thread for ILP on the atomic-return chain.
// ---------------------------------------------------------------------------
__global__ __launch_bounds__(256) void rank_kernel(
    const int* __restrict__ edges, int* __restrict__ deg,
    int* __restrict__ rank, int E)
{
    const int e0 = (blockIdx.x * 256 + threadIdx.x) * 2;
    if (e0 + 1 < E) {
        const int4 ed = ((const int4*)edges)[e0 >> 1];
        const int r0 = atomicAdd(&deg[ed.x], 1);
        const int r1 = atomicAdd(&deg[ed.z], 1);
        *(int2*)&rank[e0] = make_int2(r0, r1);
    } else if (e0 < E) {
        const int2 ed = ((const int2*)edges)[e0];
        rank[e0] = atomicAdd(&deg[ed.x], 1);
    }
}

__global__ __launch_bounds__(256) void scan1_kernel(
    const int* __restrict__ deg, int* __restrict__ off,
    int* __restrict__ bsum, int N)
{
    __shared__ int lds[256];
    const int t = threadIdx.x;
    const int base = blockIdx.x * 1024 + t * 4;
    int v[4];
    int ts = 0;
    #pragma unroll
    for (int j = 0; j < 4; ++j) {
        v[j] = (base + j < N) ? deg[base + j] : 0;
        ts += v[j];
    }
    lds[t] = ts;
    __syncthreads();
    for (int d = 1; d < 256; d <<= 1) {
        int xv = (t >= d) ? lds[t - d] : 0;
        __syncthreads();
        lds[t] += xv;
        __syncthreads();
    }
    int run = lds[t] - ts;
    #pragma unroll
    for (int j = 0; j < 4; ++j) {
        if (base + j < N) off[base + j] = run;
        run += v[j];
    }
    if (t == 255) bsum[blockIdx.x] = lds[255];
}

__global__ __launch_bounds__(256) void scan2_kernel(int* __restrict__ bsum, int nb)
{
    __shared__ int lds[256];
    const int t = threadIdx.x;
    const int v = (t < nb) ? bsum[t] : 0;
    lds[t] = v;
    __syncthreads();
    for (int d = 1; d < 256; d <<= 1) {
        int xv = (t >= d) ? lds[t - d] : 0;
        __syncthreads();
        lds[t] += xv;
        __syncthreads();
    }
    if (t < nb) bsum[t] = lds[t] - v;
}

// scan3: finalize offsets + detect bidx==arange (flag stays 0 if identity)
__global__ __launch_bounds__(256) void scan3_kernel(
    int* __restrict__ off, const int* __restrict__ bsum,
    const int* __restrict__ bidx, int* __restrict__ flag, int N, int E)
{
    const int i = blockIdx.x * 256 + threadIdx.x;
    if (i < N) {
        off[i] += bsum[i >> 10];
        if (bidx[i] != i) atomicOr(flag, 1);
    }
    if (i == 0) off[N] = E;
}

// ---------------------------------------------------------------------------
// fill: no atomic — pos = precomputed rank. Scatter only dst (4B/edge).
// ---------------------------------------------------------------------------
__global__ __launch_bounds__(256) void fill_kernel(
    const int* __restrict__ edges, const int* __restrict__ off,
    const int* __restrict__ rank, int* __restrict__ csr, int E)
{
    const int e0 = (blockIdx.x * 256 + threadIdx.x) * 2;
    if (e0 + 1 < E) {
        const int4 ed = ((const int4*)edges)[e0 >> 1];
        const int2 rk = *(const int2*)&rank[e0];
        csr[off[ed.x] + rk.x] = ed.y;
        csr[off[ed.z] + rk.y] = ed.w;
    } else if (e0 < E) {
        const int2 ed = ((const int2*)edges)[e0];
        csr[off[ed.x] + rank[e0]] = ed.y;
    }
}

// ---------------------------------------------------------------------------
// K3: gather aggregation. Wave = 4 edge-groups x 16 col-lanes.
// Score recomputed from s1/s2 (L2-resident) — no score scatter needed.
// Writes straight to out when bidx is identity (flag==0).
// ---------------------------------------------------------------------------
__global__ __launch_bounds__(256) void agg_kernel(
    const int* __restrict__ off, const int* __restrict__ csr,
    const float* __restrict__ s1, const float* __restrict__ s2,
    const __half* __restrict__ emb_h, const int* __restrict__ flag,
    float* __restrict__ results, float* __restrict__ out, int N)
{
    const int wid  = (int)((blockIdx.x * 256u + threadIdx.x) >> 6);
    const int lane = threadIdx.x & 63;
    if (wid >= N) return;
    const int eg = lane >> 4;
    const int cl = lane & 15;
    const int beg = off[wid];
    const int end = off[wid + 1];
    const float s1n = s1[wid];

    const float4* __restrict__ embrow = (const float4*)emb_h;

    float av[8];
    #pragma unroll
    for (int k = 0; k < 8; ++k) av[k] = 0.f;
    float rs = 0.f;

    for (int base = beg; base < end; base += 8) {
        #pragma unroll
        for (int q = 0; q < 2; ++q) {
            const int idx = base + q * 4 + eg;
            int d = 0;
            float sc = 0.f;
            if (idx < end) {
                d = csr[idx];
                const float ll = s1n + s2[d];
                sc = __expf(ll > 0.f ? ll : SLOPE * ll);
            }
            rs += sc;
            const float4 v = embrow[(size_t)d * 16 + cl];
            const __half2* hp = reinterpret_cast<const __half2*>(&v);
            #pragma unroll
            for (int k = 0; k < 4; ++k) {
                const float2 f = __half22float2(hp[k]);
                av[2 * k]     += sc * f.x;
                av[2 * k + 1] += sc * f.y;
            }
        }
    }

    #pragma unroll
    for (int k = 0; k < 8; ++k) {
        av[k] += __shfl_xor(av[k], 16);
        av[k] += __shfl_xor(av[k], 32);
    }
    rs += __shfl_xor(rs, 16);
    rs += __shfl_xor(rs, 32);

    const float inv = 1.f / (rs > 0.f ? rs : 1.f);
    if (eg == 0) {
        float* dbuf = (*flag == 0) ? out : results;
        float4* rp = (float4*)&dbuf[(size_t)wid * 128 + cl * 8];
        rp[0] = make_float4(av[0] * inv, av[1] * inv, av[2] * inv, av[3] * inv);
        rp[1] = make_float4(av[4] * inv, av[5] * inv, av[6] * inv, av[7] * inv);
    }
}

// ---------------------------------------------------------------------------
// K4: out[i] = results[batch_idx[i]] — skipped when identity (agg wrote out)
// ---------------------------------------------------------------------------
__global__ __launch_bounds__(256) void gather_kernel(
    const float* __restrict__ results, const int* __restrict__ bidx,
    const int* __restrict__ flag, float* __restrict__ out, int N)
{
    if (*flag == 0) return;
    const unsigned i = blockIdx.x * 256u + threadIdx.x;
    if (i >= (unsigned)N * 32u) return;
    const unsigned n = i >> 5, c = i & 31;
    ((float4*)out)[i] = ((const float4*)results)[(size_t)bidx[n] * 32 + c];
}

extern "C" void kernel_launch(void* const* d_in, const int* in_sizes, int n_in,
                              void* d_out, int out_size, void* d_ws, size_t ws_size,
                              hipStream_t stream) {
    const float* x     = (const float*)d_in[0];
    const float* W     = (const float*)d_in[1];
    const float* b     = (const float*)d_in[2];
    const float* a     = (const float*)d_in[3];
    const int*   edges = (const int*)d_in[4];
    const int*   bidx  = (const int*)d_in[5];

    const int N = in_sizes[5];
    const int E = in_sizes[4] / 2;

    float*  results = (float*)d_ws;                          // N*128
    __half* emb_h   = (__half*)(results + (size_t)N * OUT_DIM);
    float*  s1      = (float*)(emb_h + (size_t)N * OUT_DIM);
    float*  s2      = s1 + N;
    int*    deg     = (int*)(s2 + N);                        // N
    int*    flag    = deg + N;                               // 1
    int*    off     = flag + 1;                              // N+1
    int*    bsum    = off + N + 1;                           // 256
    int*    rank    = bsum + 256;                            // E
    int*    csr     = rank + E;                              // E
    short*  Whi     = (short*)(csr + E);
    short*  Wlo     = Whi + OUT_DIM * IN_DIM;

    // zero deg[N] and flag together
    hipMemsetAsync(deg, 0, (size_t)(N + 1) * sizeof(int), stream);

    wsplit_kernel<<<(OUT_DIM * IN_DIM) / 256, 256, 0, stream>>>(W, Whi, Wlo);

    dim3 gGemm((N + 127) / 128);
    gemm_emb_kernel<<<gGemm, 256, 0, stream>>>(x, Whi, Wlo, b, a, emb_h, s1, s2, N);

    const int gE2 = (E / 2 + 255) / 256 + 1;
    rank_kernel<<<gE2, 256, 0, stream>>>(edges, deg, rank, E);

    const int nb = (N + 1023) / 1024;
    scan1_kernel<<<nb, 256, 0, stream>>>(deg, off, bsum, N);
    scan2_kernel<<<1, 256, 0, stream>>>(bsum, nb);
    scan3_kernel<<<(N + 255) / 256, 256, 0, stream>>>(off, bsum, bidx, flag, N, E);

    fill_kernel<<<gE2, 256, 0, stream>>>(edges, off, rank, csr, E);

    const unsigned aggThreads = (unsigned)N * 64u;
    agg_kernel<<<(aggThreads + 255u) / 256u, 256, 0, stream>>>(
        off, csr, s1, s2, emb_h, flag, results, (float*)d_out, N);

    const unsigned gatherThreads = (unsigned)N * 32u;
    gather_kernel<<<(gatherThreads + 255u) / 256u, 256, 0, stream>>>(
        results, bidx, flag, (float*)d_out, N);
}

// Round 3
// 214.438 us; speedup vs baseline: 1.9092x; 1.1244x over previous
//
#include <hip/hip_runtime.h>
#include <hip/hip_fp16.h>

#define IN_DIM 256
#define OUT_DIM 128
#define SLOPE 0.1f

typedef __attribute__((ext_vector_type(8))) short short8;
typedef __attribute__((ext_vector_type(4))) float f32x4;

// round-to-nearest-even f32 -> bf16 bits
__device__ __forceinline__ unsigned bf16_rne(float f) {
    unsigned u = __float_as_uint(f);
    return (u + 0x7FFFu + ((u >> 16) & 1u)) >> 16;
}

// ---------------------------------------------------------------------------
// K0: pre-split W into bf16 hi/lo once
// ---------------------------------------------------------------------------
__global__ __launch_bounds__(256) void wsplit_kernel(
    const float* __restrict__ W, short* __restrict__ Whi, short* __restrict__ Wlo)
{
    const int i = blockIdx.x * 256 + threadIdx.x;   // 128*256 = 32768 elements
    const float v = W[i];
    const unsigned hb = bf16_rne(v);
    const float hf = __uint_as_float(hb << 16);
    Whi[i] = (short)hb;
    Wlo[i] = (short)bf16_rne(v - hf);
}

// ---------------------------------------------------------------------------
// Fused K1: blocks [0, nGemm) do emb = x@W^T + b (split-bf16 MFMA, fused
// s1/s2 + fp16 store); blocks [nGemm, ...) do the edge rank pass (random
// atomics). The two paths touch disjoint data and disjoint pipes (MFMA/LDS
// vs atomic latency) — co-residency overlaps them inside one dispatch.
// ---------------------------------------------------------------------------
__global__ __launch_bounds__(256) void gemm_rank_kernel(
    const float* __restrict__ x, const short* __restrict__ Whi_g,
    const short* __restrict__ Wlo_g, const float* __restrict__ bias,
    const float* __restrict__ a, __half* __restrict__ emb_h,
    float* __restrict__ s1, float* __restrict__ s2,
    const int* __restrict__ edges, int* __restrict__ deg,
    int* __restrict__ rank, int N, int E, int nGemm)
{
    __shared__ short lds[128 * 144];

    if ((int)blockIdx.x >= nGemm) {
        // ---------------- rank path: deg count + per-edge rank ----------------
        const int rb = (int)blockIdx.x - nGemm;
        const int e0 = (rb * 256 + (int)threadIdx.x) * 2;
        if (e0 + 1 < E) {
            const int4 ed = ((const int4*)edges)[e0 >> 1];
            const int r0 = atomicAdd(&deg[ed.x], 1);
            const int r1 = atomicAdd(&deg[ed.z], 1);
            *(int2*)&rank[e0] = make_int2(r0, r1);
        } else if (e0 < E) {
            const int2 ed = ((const int2*)edges)[e0];
            rank[e0] = atomicAdd(&deg[ed.x], 1);
        }
        return;
    }

    // ---------------- gemm path ----------------
    short* Ahi = lds;
    short* Alo = lds + 4096;
    short* Bhi = lds + 8192;
    short* Blo = lds + 12288;

    const int tid = threadIdx.x;
    const int l   = tid & 63;
    const int w   = tid >> 6;
    const int gm0 = blockIdx.x * 128;

    const int sm  = tid >> 1;
    const int kc0 = (tid & 1) * 2;

    f32x4 acc[2][8];
    #pragma unroll
    for (int i = 0; i < 2; ++i)
        #pragma unroll
        for (int j = 0; j < 8; ++j) acc[i][j] = (f32x4)0.f;

    float bias_v[8], av1[8], av2[8];
    #pragma unroll
    for (int nf = 0; nf < 8; ++nf) {
        const int col = nf * 16 + (l & 15);
        bias_v[nf] = bias[col];
        av1[nf]    = a[col];
        av2[nf]    = a[OUT_DIM + col];
    }

    for (int ks = 0; ks < 8; ++ks) {
        const int k0 = ks * 32;
        #pragma unroll
        for (int q = 0; q < 2; ++q) {
            const int kc = kc0 + q;
            {
                const int gm = gm0 + sm;
                float v[8];
                if (gm < N) {
                    const float4 p0 = *(const float4*)&x[(size_t)gm * IN_DIM + k0 + kc * 8];
                    const float4 p1 = *(const float4*)&x[(size_t)gm * IN_DIM + k0 + kc * 8 + 4];
                    v[0]=p0.x; v[1]=p0.y; v[2]=p0.z; v[3]=p0.w;
                    v[4]=p1.x; v[5]=p1.y; v[6]=p1.z; v[7]=p1.w;
                } else {
                    #pragma unroll
                    for (int j = 0; j < 8; ++j) v[j] = 0.f;
                }
                short8 h8, l8;
                #pragma unroll
                for (int j = 0; j < 8; ++j) {
                    unsigned hb = bf16_rne(v[j]);
                    float hf = __uint_as_float(hb << 16);
                    h8[j] = (short)hb;
                    l8[j] = (short)bf16_rne(v[j] - hf);
                }
                *(short8*)&Ahi[kc * 1024 + sm * 8] = h8;
                *(short8*)&Alo[kc * 1024 + sm * 8] = l8;
            }
            {
                const short8 h8 = *(const short8*)&Whi_g[sm * IN_DIM + k0 + kc * 8];
                const short8 l8 = *(const short8*)&Wlo_g[sm * IN_DIM + k0 + kc * 8];
                *(short8*)&Bhi[kc * 1024 + sm * 8] = h8;
                *(short8*)&Blo[kc * 1024 + sm * 8] = l8;
            }
        }
        __syncthreads();

        short8 ah[2], al[2];
        #pragma unroll
        for (int mf = 0; mf < 2; ++mf) {
            const int row = w * 32 + mf * 16 + (l & 15);
            const int off = (l >> 4) * 1024 + row * 8;
            ah[mf] = *(const short8*)&Ahi[off];
            al[mf] = *(const short8*)&Alo[off];
        }
        #pragma unroll
        for (int nf = 0; nf < 8; ++nf) {
            const int col = nf * 16 + (l & 15);
            const int off = (l >> 4) * 1024 + col * 8;
            short8 bh = *(const short8*)&Bhi[off];
            short8 bl = *(const short8*)&Blo[off];
            #pragma unroll
            for (int mf = 0; mf < 2; ++mf) {
                acc[mf][nf] = __builtin_amdgcn_mfma_f32_16x16x32_bf16(ah[mf], bh, acc[mf][nf], 0, 0, 0);
                acc[mf][nf] = __builtin_amdgcn_mfma_f32_16x16x32_bf16(al[mf], bh, acc[mf][nf], 0, 0, 0);
                acc[mf][nf] = __builtin_amdgcn_mfma_f32_16x16x32_bf16(ah[mf], bl, acc[mf][nf], 0, 0, 0);
            }
        }
        __syncthreads();
    }

    // ---- fused epilogue ----
    __half* hl = (__half*)lds;   // [128][144]
    #pragma unroll
    for (int mf = 0; mf < 2; ++mf) {
        #pragma unroll
        for (int r = 0; r < 4; ++r) {
            const int lrow = w * 32 + mf * 16 + (l >> 4) * 4 + r;
            float p1 = 0.f, p2 = 0.f;
            #pragma unroll
            for (int nf = 0; nf < 8; ++nf) {
                const float e = acc[mf][nf][r] + bias_v[nf];
                p1 += e * av1[nf];
                p2 += e * av2[nf];
                hl[lrow * 144 + nf * 16 + (l & 15)] = __float2half(e);
            }
            p1 += __shfl_xor(p1, 1); p1 += __shfl_xor(p1, 2);
            p1 += __shfl_xor(p1, 4); p1 += __shfl_xor(p1, 8);
            p2 += __shfl_xor(p2, 1); p2 += __shfl_xor(p2, 2);
            p2 += __shfl_xor(p2, 4); p2 += __shfl_xor(p2, 8);
            const int gm = gm0 + lrow;
            if ((l & 15) == 0 && gm < N) { s1[gm] = p1; s2[gm] = p2; }
        }
    }
    __syncthreads();
    #pragma unroll
    for (int i = 0; i < 8; ++i) {
        const int idx = i * 256 + tid;
        const int row = idx >> 4, seg = idx & 15;
        if (gm0 + row < N) {
            const uint4 u = *(const uint4*)&hl[row * 144 + seg * 8];
            ((uint4*)emb_h)[(size_t)(gm0 + row) * 16 + seg] = u;
        }
    }
}

__global__ __launch_bounds__(256) void scan1_kernel(
    const int* __restrict__ deg, int* __restrict__ off,
    int* __restrict__ bsum, int N)
{
    __shared__ int lds[256];
    const int t = threadIdx.x;
    const int base = blockIdx.x * 1024 + t * 4;
    int v[4];
    int ts = 0;
    #pragma unroll
    for (int j = 0; j < 4; ++j) {
        v[j] = (base + j < N) ? deg[base + j] : 0;
        ts += v[j];
    }
    lds[t] = ts;
    __syncthreads();
    for (int d = 1; d < 256; d <<= 1) {
        int xv = (t >= d) ? lds[t - d] : 0;
        __syncthreads();
        lds[t] += xv;
        __syncthreads();
    }
    int run = lds[t] - ts;
    #pragma unroll
    for (int j = 0; j < 4; ++j) {
        if (base + j < N) off[base + j] = run;
        run += v[j];
    }
    if (t == 255) bsum[blockIdx.x] = lds[255];
}

__global__ __launch_bounds__(256) void scan2_kernel(int* __restrict__ bsum, int nb)
{
    __shared__ int lds[256];
    const int t = threadIdx.x;
    const int v = (t < nb) ? bsum[t] : 0;
    lds[t] = v;
    __syncthreads();
    for (int d = 1; d < 256; d <<= 1) {
        int xv = (t >= d) ? lds[t - d] : 0;
        __syncthreads();
        lds[t] += xv;
        __syncthreads();
    }
    if (t < nb) bsum[t] = lds[t] - v;
}

// scan3: finalize offsets + detect bidx==arange (flag stays 0 if identity)
__global__ __launch_bounds__(256) void scan3_kernel(
    int* __restrict__ off, const int* __restrict__ bsum,
    const int* __restrict__ bidx, int* __restrict__ flag, int N, int E)
{
    const int i = blockIdx.x * 256 + threadIdx.x;
    if (i < N) {
        off[i] += bsum[i >> 10];
        if (bidx[i] != i) atomicOr(flag, 1);
    }
    if (i == 0) off[N] = E;
}

// ---------------------------------------------------------------------------
// fill: no atomic — pos = precomputed rank. Scatter only dst (4B/edge).
// ---------------------------------------------------------------------------
__global__ __launch_bounds__(256) void fill_kernel(
    const int* __restrict__ edges, const int* __restrict__ off,
    const int* __restrict__ rank, int* __restrict__ csr, int E)
{
    const int e0 = (blockIdx.x * 256 + threadIdx.x) * 2;
    if (e0 + 1 < E) {
        const int4 ed = ((const int4*)edges)[e0 >> 1];
        const int2 rk = *(const int2*)&rank[e0];
        csr[off[ed.x] + rk.x] = ed.y;
        csr[off[ed.z] + rk.y] = ed.w;
    } else if (e0 < E) {
        const int2 ed = ((const int2*)edges)[e0];
        csr[off[ed.x] + rank[e0]] = ed.y;
    }
}

// ---------------------------------------------------------------------------
// K3: gather aggregation. Wave = 4 edge-groups x 16 col-lanes, 16 edges per
// iteration in 4 batched phases so each lane keeps 4 independent gathers in
// flight (csr batch -> s2+score batch -> row batch -> FMA batch).
// ---------------------------------------------------------------------------
__global__ __launch_bounds__(256) void agg_kernel(
    const int* __restrict__ off, const int* __restrict__ csr,
    const float* __restrict__ s1, const float* __restrict__ s2,
    const __half* __restrict__ emb_h, const int* __restrict__ flag,
    float* __restrict__ results, float* __restrict__ out, int N)
{
    const int wid  = (int)((blockIdx.x * 256u + threadIdx.x) >> 6);
    const int lane = threadIdx.x & 63;
    if (wid >= N) return;
    const int eg = lane >> 4;
    const int cl = lane & 15;
    const int beg = off[wid];
    const int end = off[wid + 1];
    const float s1n = s1[wid];

    const float4* __restrict__ embrow = (const float4*)emb_h;

    float av[8];
    #pragma unroll
    for (int k = 0; k < 8; ++k) av[k] = 0.f;
    float rs = 0.f;

    for (int base = beg; base < end; base += 16) {
        int dq[4];
        #pragma unroll
        for (int q = 0; q < 4; ++q) {
            const int idx = base + q * 4 + eg;
            dq[q] = (idx < end) ? csr[idx] : -1;
        }
        float scq[4];
        #pragma unroll
        for (int q = 0; q < 4; ++q) {
            if (dq[q] >= 0) {
                const float ll = s1n + s2[dq[q]];
                scq[q] = __expf(ll > 0.f ? ll : SLOPE * ll);
            } else {
                scq[q] = 0.f;
                dq[q]  = 0;
            }
        }
        float4 vq[4];
        #pragma unroll
        for (int q = 0; q < 4; ++q)
            vq[q] = embrow[(size_t)dq[q] * 16 + cl];
        #pragma unroll
        for (int q = 0; q < 4; ++q) {
            rs += scq[q];
            const __half2* hp = reinterpret_cast<const __half2*>(&vq[q]);
            #pragma unroll
            for (int k = 0; k < 4; ++k) {
                const float2 f = __half22float2(hp[k]);
                av[2 * k]     += scq[q] * f.x;
                av[2 * k + 1] += scq[q] * f.y;
            }
        }
    }

    #pragma unroll
    for (int k = 0; k < 8; ++k) {
        av[k] += __shfl_xor(av[k], 16);
        av[k] += __shfl_xor(av[k], 32);
    }
    rs += __shfl_xor(rs, 16);
    rs += __shfl_xor(rs, 32);

    const float inv = 1.f / (rs > 0.f ? rs : 1.f);
    if (eg == 0) {
        float* dbuf = (*flag == 0) ? out : results;
        float4* rp = (float4*)&dbuf[(size_t)wid * 128 + cl * 8];
        rp[0] = make_float4(av[0] * inv, av[1] * inv, av[2] * inv, av[3] * inv);
        rp[1] = make_float4(av[4] * inv, av[5] * inv, av[6] * inv, av[7] * inv);
    }
}

// ---------------------------------------------------------------------------
// K4: out[i] = results[batch_idx[i]] — skipped when identity (agg wrote out)
// ---------------------------------------------------------------------------
__global__ __launch_bounds__(256) void gather_kernel(
    const float* __restrict__ results, const int* __restrict__ bidx,
    const int* __restrict__ flag, float* __restrict__ out, int N)
{
    if (*flag == 0) return;
    const unsigned i = blockIdx.x * 256u + threadIdx.x;
    if (i >= (unsigned)N * 32u) return;
    const unsigned n = i >> 5, c = i & 31;
    ((float4*)out)[i] = ((const float4*)results)[(size_t)bidx[n] * 32 + c];
}

extern "C" void kernel_launch(void* const* d_in, const int* in_sizes, int n_in,
                              void* d_out, int out_size, void* d_ws, size_t ws_size,
                              hipStream_t stream) {
    const float* x     = (const float*)d_in[0];
    const float* W     = (const float*)d_in[1];
    const float* b     = (const float*)d_in[2];
    const float* a     = (const float*)d_in[3];
    const int*   edges = (const int*)d_in[4];
    const int*   bidx  = (const int*)d_in[5];

    const int N = in_sizes[5];
    const int E = in_sizes[4] / 2;

    float*  results = (float*)d_ws;                          // N*128
    __half* emb_h   = (__half*)(results + (size_t)N * OUT_DIM);
    float*  s1      = (float*)(emb_h + (size_t)N * OUT_DIM);
    float*  s2      = s1 + N;
    int*    deg     = (int*)(s2 + N);                        // N
    int*    flag    = deg + N;                               // 1
    int*    off     = flag + 1;                              // N+1
    int*    bsum    = off + N + 1;                           // 256
    int*    rank    = bsum + 256;                            // E
    int*    csr     = rank + E;                              // E
    short*  Whi     = (short*)(csr + E);
    short*  Wlo     = Whi + OUT_DIM * IN_DIM;

    // zero deg[N] and flag together
    hipMemsetAsync(deg, 0, (size_t)(N + 1) * sizeof(int), stream);

    wsplit_kernel<<<(OUT_DIM * IN_DIM) / 256, 256, 0, stream>>>(W, Whi, Wlo);

    const int nGemm = (N + 127) / 128;
    const int gE2   = (E / 2 + 255) / 256 + 1;
    gemm_rank_kernel<<<nGemm + gE2, 256, 0, stream>>>(
        x, Whi, Wlo, b, a, emb_h, s1, s2, edges, deg, rank, N, E, nGemm);

    const int nb = (N + 1023) / 1024;
    scan1_kernel<<<nb, 256, 0, stream>>>(deg, off, bsum, N);
    scan2_kernel<<<1, 256, 0, stream>>>(bsum, nb);
    scan3_kernel<<<(N + 255) / 256, 256, 0, stream>>>(off, bsum, bidx, flag, N, E);

    fill_kernel<<<gE2, 256, 0, stream>>>(edges, off, rank, csr, E);

    const unsigned aggThreads = (unsigned)N * 64u;
    agg_kernel<<<(aggThreads + 255u) / 256u, 256, 0, stream>>>(
        off, csr, s1, s2, emb_h, flag, results, (float*)d_out, N);

    const unsigned gatherThreads = (unsigned)N * 32u;
    gather_kernel<<<(gatherThreads + 255u) / 256u, 256, 0, stream>>>(
        results, bidx, flag, (float*)d_out, N);
}